// Round 9
// baseline (73.086 us; speedup 1.0000x reference)
//
#include <hip/hip_runtime.h>
#include <cstdint>
#include <cstddef>

typedef float  f32x4  __attribute__((ext_vector_type(4)));
typedef long long i64;
typedef unsigned char uchar;

#define N_ROWS 8192
#define KDIM   256
#define TEMP_INV 2.0f
#define LOG2E  1.4426950408889634f
#define EXPC   (TEMP_INV * LOG2E)

// ---------------- Kernel A: label ranking / permutation (1 block, 1024 thr)
__global__ __launch_bounds__(1024) void build_perm(const int* __restrict__ label,
        int* __restrict__ perm, int* __restrict__ labelPerm,
        int* __restrict__ classStart, int* __restrict__ cumTiles)
{
    __shared__ unsigned short lcnt[1024][10];
    __shared__ int cstart[11];
    __shared__ int ccount[10];
    const int tid = threadIdx.x;
    const int wave = tid >> 6, lane = tid & 63;

    int lab[8];
    #pragma unroll
    for (int j = 0; j < 8; ++j) {
        int c = label[tid + j * 1024];
        lab[j] = (c < 0) ? 0 : (c > 9 ? 9 : c);
    }
    unsigned short loc[10] = {0,0,0,0,0,0,0,0,0,0};
    #pragma unroll
    for (int j = 0; j < 8; ++j) loc[lab[j]]++;
    #pragma unroll
    for (int c = 0; c < 10; ++c) lcnt[tid][c] = loc[c];
    __syncthreads();

    if (wave < 10) {  // one wave per class: scan 1024 counts
        const int c = wave;
        int s[16]; int tot = 0;
        #pragma unroll
        for (int m = 0; m < 16; ++m) { s[m] = lcnt[lane * 16 + m][c]; tot += s[m]; }
        int incl = tot;
        #pragma unroll
        for (int d = 1; d < 64; d <<= 1) {
            int up = __shfl_up(incl, d, 64);
            if (lane >= d) incl += up;
        }
        int run = incl - tot;
        #pragma unroll
        for (int m = 0; m < 16; ++m) { lcnt[lane * 16 + m][c] = (unsigned short)run; run += s[m]; }
        if (lane == 63) ccount[c] = incl;
    }
    __syncthreads();

    if (tid == 0) {
        int run = 0, runT = 0;
        for (int c = 0; c < 10; ++c) {
            cstart[c] = run; classStart[c] = run;
            int tpc = (ccount[c] + 127) >> 7;
            cumTiles[c] = runT;
            run  += ccount[c];
            runT += tpc * (tpc + 1) / 2;     // upper-tri within class (symmetry)
        }
        cstart[10] = run; classStart[10] = run; cumTiles[10] = runT;
    }
    __syncthreads();

    int ofs[10];
    #pragma unroll
    for (int c = 0; c < 10; ++c) ofs[c] = lcnt[tid][c];
    #pragma unroll
    for (int j = 0; j < 8; ++j) {
        int c = lab[j];
        int pos = cstart[c] + ofs[c]++;
        perm[pos] = tid + j * 1024;
        labelPerm[pos] = c;
    }
}

// ---------------- Kernel B: normalize + permute + fp8 cast only ------------
__global__ __launch_bounds__(256) void normalize_rows(const float* __restrict__ logits,
        const int* __restrict__ perm, uchar* __restrict__ xn8)
{
    const int p = blockIdx.x * 4 + (threadIdx.x >> 6);
    const int lane = threadIdx.x & 63;
    const int old = perm[p];
    float4 v = reinterpret_cast<const float4*>(logits + (size_t)old * KDIM)[lane];
    float ss = v.x*v.x + v.y*v.y + v.z*v.z + v.w*v.w;
    #pragma unroll
    for (int off = 32; off >= 1; off >>= 1) ss += __shfl_xor(ss, off, 64);
    float inv = 1.0f / fmaxf(sqrtf(ss), 1e-8f);
    float x0 = v.x * inv, x1 = v.y * inv, x2 = v.z * inv, x3 = v.w * inv;
    int pk = __builtin_amdgcn_cvt_pk_fp8_f32(x0, x1, 0, false);
    pk     = __builtin_amdgcn_cvt_pk_fp8_f32(x2, x3, pk, true);
    reinterpret_cast<unsigned int*>(xn8 + (size_t)p * KDIM)[lane] = (unsigned int)pk;
}

// ================= fp8 4-wave 128-tile core (phase1 + phase3) ===============
// LDS tile: 128 rows x 64 B (BK=64 fp8). 16B chunk swizzle: slot = c ^ (row&3),
// linear LDS dest + pre-swizzled global source (rule #21).
__device__ __forceinline__ void stage_pair_fp8(const uchar* __restrict__ xn8,
        int rowBase, int colBase, int kb, uchar* As, uchar* Bs, int wave, int lane)
{
    #pragma unroll
    for (int it = 0; it < 2; ++it) {
        int ci = it * 256 + wave * 64 + lane;          // 16B chunk in [0,512)
        int row = ci >> 2;
        int c = (ci & 3) ^ (row & 3);
        const uchar* gA = xn8 + (size_t)(rowBase + row) * KDIM + kb + c * 16;
        const uchar* gB = xn8 + (size_t)(colBase + row) * KDIM + kb + c * 16;
        uchar* lA = As + (size_t)ci * 16;
        uchar* lB = Bs + (size_t)ci * 16;
        __builtin_amdgcn_global_load_lds((const __attribute__((address_space(1))) void*)gA,
                                         (__attribute__((address_space(3))) void*)lA, 16, 0, 0);
        __builtin_amdgcn_global_load_lds((const __attribute__((address_space(1))) void*)gB,
                                         (__attribute__((address_space(3))) void*)lB, 16, 0, 0);
    }
}

__device__ __forceinline__ void read_frags8(const uchar* As, const uchar* Bs,
        i64 (&a)[2][4], i64 (&b)[2][4], int wave, int lane)
{
    const int wr = wave >> 1, wc = wave & 1;
    const int lrow = lane & 15, kgrp = lane >> 4;
    const int ch = kgrp >> 1, half = kgrp & 1;
    #pragma unroll
    for (int kk = 0; kk < 2; ++kk) {
        const int c16 = kk * 2 + ch;                   // logical 16B chunk
        #pragma unroll
        for (int mi = 0; mi < 4; ++mi) {
            const int row = wr*64 + mi*16 + lrow;
            a[kk][mi] = *reinterpret_cast<const i64*>(As + (size_t)row * 64 + ((c16 ^ (row & 3)) * 16) + half * 8);
        }
        #pragma unroll
        for (int ni = 0; ni < 4; ++ni) {
            const int row = wc*64 + ni*16 + lrow;
            b[kk][ni] = *reinterpret_cast<const i64*>(Bs + (size_t)row * 64 + ((c16 ^ (row & 3)) * 16) + half * 8);
        }
    }
}

__device__ __forceinline__ void mfma_frags8(i64 (&a)[2][4], i64 (&b)[2][4], f32x4 (&acc)[4][4])
{
    #pragma unroll
    for (int kk = 0; kk < 2; ++kk)
        #pragma unroll
        for (int mi = 0; mi < 4; ++mi)
            #pragma unroll
            for (int ni = 0; ni < 4; ++ni)
                acc[mi][ni] = __builtin_amdgcn_mfma_f32_16x16x32_fp8_fp8(a[kk][mi], b[kk][ni], acc[mi][ni], 0, 0, 0);
}

#define PIPE8_READS_RELEASE(Ac, Bc)                                  \
    i64 a[2][4], b[2][4];                                            \
    read_frags8(Ac, Bc, a, b, wave, lane);                           \
    __builtin_amdgcn_sched_barrier(0);                               \
    asm volatile("s_waitcnt lgkmcnt(0)" ::: "memory");               \
    __builtin_amdgcn_sched_barrier(0);                               \
    __builtin_amdgcn_s_barrier();                                    \
    __builtin_amdgcn_sched_barrier(0);

#define PIPE8_MFMA()                                                 \
    __builtin_amdgcn_s_setprio(1);                                   \
    mfma_frags8(a, b, acc);                                          \
    __builtin_amdgcn_s_setprio(0);

#define PIPE8_TAIL(N)                                                \
    __builtin_amdgcn_sched_barrier(0);                               \
    asm volatile("s_waitcnt vmcnt(" #N ")" ::: "memory");            \
    __builtin_amdgcn_s_barrier();                                    \
    __builtin_amdgcn_sched_barrier(0);

__device__ __forceinline__ void kloop_fp8(const uchar* __restrict__ xn8,
        int rowBase, int colBase, f32x4 (&acc)[4][4],
        uchar* As0, uchar* Bs0, uchar* As1, uchar* Bs1, int wave, int lane)
{
    stage_pair_fp8(xn8, rowBase, colBase, 0,  As0, Bs0, wave, lane);  // 4 loads
    stage_pair_fp8(xn8, rowBase, colBase, 64, As1, Bs1, wave, lane);  // 4 loads
    asm volatile("s_waitcnt vmcnt(4)" ::: "memory");                  // S0 landed
    __builtin_amdgcn_s_barrier();
    __builtin_amdgcn_sched_barrier(0);
    {
        PIPE8_READS_RELEASE(As0, Bs0)
        stage_pair_fp8(xn8, rowBase, colBase, 128, As0, Bs0, wave, lane);
        PIPE8_MFMA()
        PIPE8_TAIL(4)                                                 // S1 landed
    }
    {
        PIPE8_READS_RELEASE(As1, Bs1)
        stage_pair_fp8(xn8, rowBase, colBase, 192, As1, Bs1, wave, lane);
        PIPE8_MFMA()
        PIPE8_TAIL(4)                                                 // S2 landed
    }
    {
        PIPE8_READS_RELEASE(As0, Bs0)
        PIPE8_MFMA()
        PIPE8_TAIL(0)                                                 // S3 landed
    }
    {
        PIPE8_READS_RELEASE(As1, Bs1)   // release barrier frees pool for epilogue
        PIPE8_MFMA()
    }
}

// ---------------- Kernel C: upper-tri 128-tiles (fp8) -> pD partials --------
__global__ __launch_bounds__(256, 4) void phase1_gemm(const uchar* __restrict__ xn8,
        const int* __restrict__ labelPerm, float* __restrict__ pD)
{
    __shared__ __align__(16) char pool[32768];
    uchar* As0 = (uchar*)(pool);
    uchar* Bs0 = (uchar*)(pool + 8192);
    uchar* As1 = (uchar*)(pool + 16384);
    uchar* Bs1 = (uchar*)(pool + 24576);
    float* rowD = (float*)pool;            // [128][32], aliases pool post-release
    float* colD = (float*)(pool + 16384);  // [128][8]
    __shared__ int labLDS[256];

    const int tid = threadIdx.x;
    const int wave = tid >> 6, lane = tid & 63;

    int t = blockIdx.x, bi = 0;
    while (t >= 64 - bi) { t -= 64 - bi; ++bi; }
    const int bj = bi + t;
    const bool isDiag = (bi == bj);
    const int rowBase = bi * 128, colBase = bj * 128;

    // rows are class-sorted: tile is entirely one class iff first row label
    // == last col label -> every pair same-label -> contributes 0 to D.
    if (labelPerm[rowBase] == labelPerm[colBase + 127]) {
        if (tid < 128)       pD[(size_t)bj * N_ROWS + rowBase + tid] = 0.f;
        else if (!isDiag)    pD[(size_t)bi * N_ROWS + colBase + tid - 128] = 0.f;
        return;
    }

    labLDS[tid] = labelPerm[(tid < 128) ? (rowBase + tid) : (colBase + tid - 128)];
    __builtin_amdgcn_sched_barrier(0);

    f32x4 acc[4][4] = {};
    kloop_fp8(xn8, rowBase, colBase, acc, As0, Bs0, As1, Bs1, wave, lane);

    const int wr = wave >> 1, wc = wave & 1;
    const int lrow = lane & 15, lgrp = lane >> 4;
    float colAcc[4] = {0.f, 0.f, 0.f, 0.f};
    #pragma unroll
    for (int mi = 0; mi < 4; ++mi) {
        #pragma unroll
        for (int reg = 0; reg < 4; ++reg) {
            const int tr = wr * 64 + mi * 16 + lgrp * 4 + reg;
            const int rl = labLDS[tr];
            float rowAcc = 0.f;
            #pragma unroll
            for (int ni = 0; ni < 4; ++ni) {
                const int tc = wc * 64 + ni * 16 + lrow;
                float e = __builtin_amdgcn_exp2f(acc[mi][ni][reg] * EXPC);
                float ed = (rl != labLDS[128 + tc]) ? e : 0.f;
                rowAcc += ed;
                colAcc[ni] += ed;
            }
            rowD[tr * 32 + wc * 16 + lrow] = rowAcc;
        }
    }
    if (!isDiag) {
        #pragma unroll
        for (int ni = 0; ni < 4; ++ni) {
            const int tc = wc * 64 + ni * 16 + lrow;
            colD[tc * 8 + wr * 4 + lgrp] = colAcc[ni];
        }
    }
    __syncthreads();

    if (tid < 128) {
        const float* p = rowD + tid * 32;
        float s = 0.f;
        #pragma unroll
        for (int k = 0; k < 8; ++k) {
            f32x4 v = *reinterpret_cast<const f32x4*>(p + k * 4);
            s += v[0] + v[1] + v[2] + v[3];
        }
        pD[(size_t)bj * N_ROWS + rowBase + tid] = s;
    } else if (!isDiag) {
        const int c2 = tid - 128;
        const float* p = colD + c2 * 8;
        f32x4 v0 = *reinterpret_cast<const f32x4*>(p);
        f32x4 v1 = *reinterpret_cast<const f32x4*>(p + 4);
        pD[(size_t)bi * N_ROWS + colBase + c2] =
            v0[0] + v0[1] + v0[2] + v0[3] + v1[0] + v1[1] + v1[2] + v1[3];
    }
}

// ---------------- Kernel D: same-class upper-tri tiles -> log terms ---------
// Symmetric: off-diag tile (ti<tj) emits BOTH (r,c) and (c,r) log terms from
// one GEMM (sim symmetric; D_r vs D_c differ). fp8 core; Darr gathered per
// block from pD (fixed order).
__global__ __launch_bounds__(256, 4) void phase3_loss(const uchar* __restrict__ xn8,
        const float* __restrict__ pD, const int* __restrict__ classStart,
        const int* __restrict__ cumTiles, float* __restrict__ partial)
{
    __shared__ __align__(16) char pool[32768];
    uchar* As0 = (uchar*)(pool);
    uchar* Bs0 = (uchar*)(pool + 8192);
    uchar* As1 = (uchar*)(pool + 16384);
    uchar* Bs1 = (uchar*)(pool + 24576);
    __shared__ float redF[256];
    __shared__ float DarrH[256];
    __shared__ float DarrR[128];
    __shared__ float DarrC[128];
    __shared__ int   meta[22];

    const int tid = threadIdx.x;
    const int wave = tid >> 6, lane = tid & 63;
    const int b = blockIdx.x;

    if (tid < 11) { meta[tid] = classStart[tid]; meta[11 + tid] = cumTiles[tid]; }
    __syncthreads();
    const int nTiles = meta[11 + 10];
    if (b >= nTiles) return;

    int c = 0;
    while (c < 9 && b >= meta[11 + c + 1]) ++c;
    const int s = meta[c], e = meta[c + 1];
    const int nc = e - s;
    const int tps = (nc + 127) >> 7;
    int lt = b - meta[11 + c];
    int ti = 0;
    while (lt >= tps - ti) { lt -= tps - ti; ++ti; }
    const int tj = ti + lt;
    const bool isDiagT = (ti == tj);
    const int rowBase = s + ti * 128, colBase = s + tj * 128;

    // Darr gather: row range (and col range if off-diag); fixed order.
    {
        int r = rowBase + (tid & 127); if (r > N_ROWS - 1) r = N_ROWS - 1;
        const int half = tid >> 7;
        float d = 0.f;
        #pragma unroll 4
        for (int sl = half * 32; sl < half * 32 + 32; ++sl)
            d += pD[(size_t)sl * N_ROWS + r];
        DarrH[(tid & 127) * 2 + half] = d;
    }
    __syncthreads();
    if (tid < 128) DarrR[tid] = DarrH[tid * 2] + DarrH[tid * 2 + 1];
    __syncthreads();
    if (!isDiagT) {
        int r = colBase + (tid & 127); if (r > N_ROWS - 1) r = N_ROWS - 1;
        const int half = tid >> 7;
        float d = 0.f;
        #pragma unroll 4
        for (int sl = half * 32; sl < half * 32 + 32; ++sl)
            d += pD[(size_t)sl * N_ROWS + r];
        DarrH[(tid & 127) * 2 + half] = d;
        __syncthreads();
        if (tid < 128) DarrC[tid] = DarrH[tid * 2] + DarrH[tid * 2 + 1];
    }
    asm volatile("s_waitcnt vmcnt(0)" ::: "memory");   // clean vmcnt ledger
    __syncthreads();

    f32x4 acc[4][4] = {};
    kloop_fp8(xn8, rowBase, colBase, acc, As0, Bs0, As1, Bs1, wave, lane);

    const int wr = wave >> 1, wc = wave & 1;
    const int lrow = lane & 15, lgrp = lane >> 4;
    float lsum = 0.f;
    #pragma unroll
    for (int mi = 0; mi < 4; ++mi) {
        #pragma unroll
        for (int reg = 0; reg < 4; ++reg) {
            const int tr = wr * 64 + mi * 16 + lgrp * 4 + reg;
            const int r = rowBase + tr;
            if (r < e) {
                const float Dr = DarrR[tr];
                #pragma unroll
                for (int ni = 0; ni < 4; ++ni) {
                    const int tc = wc * 64 + ni * 16 + lrow;
                    const int cg = colBase + tc;
                    if (cg < e) {
                        float sim = acc[mi][ni][reg];
                        float ev = __builtin_amdgcn_exp2f(sim * EXPC);
                        if (isDiagT) {
                            if (cg != r)
                                lsum += __logf(ev + Dr) - TEMP_INV * sim;
                        } else {
                            lsum += __logf(ev + Dr) + __logf(ev + DarrC[tc])
                                  - 2.0f * TEMP_INV * sim;
                        }
                    }
                }
            }
        }
    }
    redF[tid] = lsum;
    __syncthreads();
    for (int st = 128; st > 0; st >>= 1) {
        if (tid < st) redF[tid] += redF[tid + st];
        __syncthreads();
    }
    if (tid == 0) partial[b] = redF[0];
}

// ---------------- Kernel E: deterministic final reduction + scale ----------
__global__ void phase4_final(const float* __restrict__ partial, const int* __restrict__ cumTiles,
                             float* __restrict__ out)
{
    __shared__ float red[256];
    const int tid = threadIdx.x;
    const int nTiles = cumTiles[10];
    float s = 0.f;
    for (int i = tid; i < nTiles; i += 256) s += partial[i];
    red[tid] = s;
    __syncthreads();
    for (int st = 128; st > 0; st >>= 1) {
        if (tid < st) red[tid] += red[tid + st];
        __syncthreads();
    }
    if (tid == 0) out[0] = red[0] * (1.0f / 16384.0f);
}

extern "C" void kernel_launch(void* const* d_in, const int* in_sizes, int n_in,
                              void* d_out, int out_size, void* d_ws, size_t ws_size,
                              hipStream_t stream)
{
    const float* logits = (const float*)d_in[0];
    const int*   label  = (const int*)d_in[1];
    float* out = (float*)d_out;

    char* ws = (char*)d_ws;
    uchar*  xn8       = (uchar*)(ws);                           // 2 MB
    float*  pD        = (float*)(ws + (2u << 20));              // 2 MB
    int*    perm      = (int*)(ws + (4u << 20));                // 32 KB
    int*    labelPerm = (int*)(ws + (4u << 20) + (32u << 10));  // 32 KB
    int*    classStart= (int*)(ws + (4u << 20) + (64u << 10));  // 64 B
    int*    cumTiles  = (int*)(ws + (4u << 20) + (64u << 10) + 256); // 64 B
    float*  partial   = (float*)(ws + (4u << 20) + (128u << 10));    // 16 KB

    hipLaunchKernelGGL(build_perm, dim3(1), dim3(1024), 0, stream,
                       label, perm, labelPerm, classStart, cumTiles);
    hipLaunchKernelGGL(normalize_rows, dim3(2048), dim3(256), 0, stream,
                       logits, perm, xn8);
    hipLaunchKernelGGL(phase1_gemm, dim3(2080), dim3(256), 0, stream,
                       xn8, labelPerm, pD);
    hipLaunchKernelGGL(phase3_loss, dim3(2080), dim3(256), 0, stream,
                       xn8, pD, classStart, cumTiles, partial);
    hipLaunchKernelGGL(phase4_final, dim3(1), dim3(256), 0, stream,
                       partial, cumTiles, out);
}

// Round 10
// 72.368 us; speedup vs baseline: 1.0099x; 1.0099x over previous
//
#include <hip/hip_runtime.h>
#include <cstdint>
#include <cstddef>

typedef float  f32x4  __attribute__((ext_vector_type(4)));
typedef long long i64;
typedef unsigned char uchar;

#define N_ROWS 8192
#define KDIM   256
#define TEMP_INV 2.0f
#define LOG2E  1.4426950408889634f
#define EXPC   (TEMP_INV * LOG2E)

#define AS1 __attribute__((address_space(1)))
#define AS3 __attribute__((address_space(3)))

// ---------------- Kernel 1: fused prep ----------------
// Blocks 0..2047: normalize+fp8-cast rows UNPERMUTED (pure elementwise).
// Block 2048: build class-sort permutation (R4-validated 256-thread version).
__global__ __launch_bounds__(256) void prep(const float* __restrict__ logits,
        const int* __restrict__ label, uchar* __restrict__ xn8,
        int* __restrict__ perm, int* __restrict__ labelPerm,
        int* __restrict__ classStart, int* __restrict__ cumTiles)
{
    __shared__ int lcnt[256][10];
    __shared__ int cstart[11];
    __shared__ int ccount[10];
    const int tid = threadIdx.x;
    const int bid = blockIdx.x;

    if (bid < 2048) {   // normalize path (no perm dependency)
        const int p = bid * 4 + (tid >> 6);
        const int lane = tid & 63;
        float4 v = reinterpret_cast<const float4*>(logits + (size_t)p * KDIM)[lane];
        float ss = v.x*v.x + v.y*v.y + v.z*v.z + v.w*v.w;
        #pragma unroll
        for (int off = 32; off >= 1; off >>= 1) ss += __shfl_xor(ss, off, 64);
        float inv = 1.0f / fmaxf(sqrtf(ss), 1e-8f);
        int pk = __builtin_amdgcn_cvt_pk_fp8_f32(v.x * inv, v.y * inv, 0, false);
        pk     = __builtin_amdgcn_cvt_pk_fp8_f32(v.z * inv, v.w * inv, pk, true);
        reinterpret_cast<unsigned int*>(xn8 + (size_t)p * KDIM)[lane] = (unsigned int)pk;
        return;
    }

    // ---- permutation build (one block) ----
    const int wave = tid >> 6, lane = tid & 63;
    const int beg = tid * 32, end = beg + 32;
    int loc[10] = {0,0,0,0,0,0,0,0,0,0};
    for (int i = beg; i < end; ++i) {
        int c = label[i]; c = (c < 0) ? 0 : (c > 9 ? 9 : c);
        loc[c]++;
    }
    #pragma unroll
    for (int c = 0; c < 10; ++c) lcnt[tid][c] = loc[c];
    __syncthreads();

    for (int c = wave; c < 10; c += 4) {
        int s0 = lcnt[lane*4+0][c], s1 = lcnt[lane*4+1][c];
        int s2 = lcnt[lane*4+2][c], s3 = lcnt[lane*4+3][c];
        int tot = s0 + s1 + s2 + s3;
        int incl = tot;
        #pragma unroll
        for (int d = 1; d < 64; d <<= 1) {
            int up = __shfl_up(incl, d, 64);
            if (lane >= d) incl += up;
        }
        int excl = incl - tot;
        lcnt[lane*4+0][c] = excl;
        lcnt[lane*4+1][c] = excl + s0;
        lcnt[lane*4+2][c] = excl + s0 + s1;
        lcnt[lane*4+3][c] = excl + s0 + s1 + s2;
        if (lane == 63) ccount[c] = incl;
    }
    __syncthreads();

    if (tid == 0) {
        int run = 0, runT = 0;
        for (int c = 0; c < 10; ++c) {
            cstart[c] = run; classStart[c] = run;
            int tpc = (ccount[c] + 127) >> 7;
            cumTiles[c] = runT;
            run  += ccount[c];
            runT += tpc * (tpc + 1) / 2;     // upper-tri within class (symmetry)
        }
        cstart[10] = run; classStart[10] = run; cumTiles[10] = runT;
    }
    __syncthreads();

    int ofs[10];
    #pragma unroll
    for (int c = 0; c < 10; ++c) ofs[c] = lcnt[tid][c];
    for (int i = beg; i < end; ++i) {
        int c = label[i]; c = (c < 0) ? 0 : (c > 9 ? 9 : c);
        int pos = cstart[c] + ofs[c]++;
        perm[pos] = i;
        labelPerm[pos] = c;
    }
}

// ================= fp8 4-wave 128-tile core (perm-indirect staging) =========
// xn8 is UNPERMUTED; per-lane source row resolved once per tile via perm[].
// LDS tile 128x64B, chunk swizzle slot = c ^ (row&3) (rule #21: linear LDS
// dest + pre-swizzled global source + same XOR on ds_read).
__device__ __forceinline__ void stage2(const uchar* sA0, const uchar* sA1,
        const uchar* sB0, const uchar* sB1, int kb,
        uchar* As, uchar* Bs, int lo0, int lo1)
{
    __builtin_amdgcn_global_load_lds((const AS1 void*)(sA0 + kb), (AS3 void*)(As + lo0), 16, 0, 0);
    __builtin_amdgcn_global_load_lds((const AS1 void*)(sA1 + kb), (AS3 void*)(As + lo1), 16, 0, 0);
    __builtin_amdgcn_global_load_lds((const AS1 void*)(sB0 + kb), (AS3 void*)(Bs + lo0), 16, 0, 0);
    __builtin_amdgcn_global_load_lds((const AS1 void*)(sB1 + kb), (AS3 void*)(Bs + lo1), 16, 0, 0);
}

__device__ __forceinline__ void read_frags8(const uchar* As, const uchar* Bs,
        i64 (&a)[2][4], i64 (&b)[2][4], int wave, int lane)
{
    const int wr = wave >> 1, wc = wave & 1;
    const int lrow = lane & 15, kgrp = lane >> 4;
    const int ch = kgrp >> 1, half = kgrp & 1;
    #pragma unroll
    for (int kk = 0; kk < 2; ++kk) {
        const int c16 = kk * 2 + ch;
        #pragma unroll
        for (int mi = 0; mi < 4; ++mi) {
            const int row = wr*64 + mi*16 + lrow;
            a[kk][mi] = *reinterpret_cast<const i64*>(As + (size_t)row * 64 + ((c16 ^ (row & 3)) * 16) + half * 8);
        }
        #pragma unroll
        for (int ni = 0; ni < 4; ++ni) {
            const int row = wc*64 + ni*16 + lrow;
            b[kk][ni] = *reinterpret_cast<const i64*>(Bs + (size_t)row * 64 + ((c16 ^ (row & 3)) * 16) + half * 8);
        }
    }
}

__device__ __forceinline__ void mfma_frags8(i64 (&a)[2][4], i64 (&b)[2][4], f32x4 (&acc)[4][4])
{
    #pragma unroll
    for (int kk = 0; kk < 2; ++kk)
        #pragma unroll
        for (int mi = 0; mi < 4; ++mi)
            #pragma unroll
            for (int ni = 0; ni < 4; ++ni)
                acc[mi][ni] = __builtin_amdgcn_mfma_f32_16x16x32_fp8_fp8(a[kk][mi], b[kk][ni], acc[mi][ni], 0, 0, 0);
}

#define PIPE8_READS_RELEASE(Ac, Bc)                                  \
    i64 a[2][4], b[2][4];                                            \
    read_frags8(Ac, Bc, a, b, wave, lane);                           \
    __builtin_amdgcn_sched_barrier(0);                               \
    asm volatile("s_waitcnt lgkmcnt(0)" ::: "memory");               \
    __builtin_amdgcn_sched_barrier(0);                               \
    __builtin_amdgcn_s_barrier();                                    \
    __builtin_amdgcn_sched_barrier(0);

#define PIPE8_MFMA()                                                 \
    __builtin_amdgcn_s_setprio(1);                                   \
    mfma_frags8(a, b, acc);                                          \
    __builtin_amdgcn_s_setprio(0);

#define PIPE8_TAIL(N)                                                \
    __builtin_amdgcn_sched_barrier(0);                               \
    asm volatile("s_waitcnt vmcnt(" #N ")" ::: "memory");            \
    __builtin_amdgcn_s_barrier();                                    \
    __builtin_amdgcn_sched_barrier(0);

// Per-tile precomputed per-lane sources (sA0..sB1, lo0/lo1) -> same 4-loads-
// per-stage ledger as the validated R8/R9 pipeline.
#define KLOOP_FP8()                                                           \
    stage2(sA0, sA1, sB0, sB1, 0,   As0, Bs0, lo0, lo1);                      \
    stage2(sA0, sA1, sB0, sB1, 64,  As1, Bs1, lo0, lo1);                      \
    asm volatile("s_waitcnt vmcnt(4)" ::: "memory");                          \
    __builtin_amdgcn_s_barrier();                                             \
    __builtin_amdgcn_sched_barrier(0);                                        \
    {                                                                         \
        PIPE8_READS_RELEASE(As0, Bs0)                                         \
        stage2(sA0, sA1, sB0, sB1, 128, As0, Bs0, lo0, lo1);                  \
        PIPE8_MFMA()                                                          \
        PIPE8_TAIL(4)                                                         \
    }                                                                         \
    {                                                                         \
        PIPE8_READS_RELEASE(As1, Bs1)                                         \
        stage2(sA0, sA1, sB0, sB1, 192, As1, Bs1, lo0, lo1);                  \
        PIPE8_MFMA()                                                          \
        PIPE8_TAIL(4)                                                         \
    }                                                                         \
    {                                                                         \
        PIPE8_READS_RELEASE(As0, Bs0)                                         \
        PIPE8_MFMA()                                                          \
        PIPE8_TAIL(0)                                                         \
    }                                                                         \
    {                                                                         \
        PIPE8_READS_RELEASE(As1, Bs1)                                         \
        PIPE8_MFMA()                                                          \
    }

#define TILE_SRC_SETUP(rowBase, colBase)                                      \
    const int ci0 = wave * 64 + lane, ci1 = 256 + wave * 64 + lane;           \
    const int r0 = ci0 >> 2, r1 = ci1 >> 2;                                   \
    const int c0 = (ci0 & 3) ^ (r0 & 3), c1 = (ci1 & 3) ^ (r1 & 3);           \
    const uchar* sA0 = xn8 + (size_t)perm[(rowBase) + r0] * KDIM + c0 * 16;   \
    const uchar* sA1 = xn8 + (size_t)perm[(rowBase) + r1] * KDIM + c1 * 16;   \
    const uchar* sB0 = xn8 + (size_t)perm[(colBase) + r0] * KDIM + c0 * 16;   \
    const uchar* sB1 = xn8 + (size_t)perm[(colBase) + r1] * KDIM + c1 * 16;   \
    const int lo0 = ci0 * 16, lo1 = ci1 * 16;

// ---------------- Kernel 2: upper-tri 128-tiles (fp8) -> pD partials --------
__global__ __launch_bounds__(256, 4) void phase1_gemm(const uchar* __restrict__ xn8,
        const int* __restrict__ perm, const int* __restrict__ labelPerm,
        float* __restrict__ pD)
{
    __shared__ __align__(16) char pool[32768];
    uchar* As0 = (uchar*)(pool);
    uchar* Bs0 = (uchar*)(pool + 8192);
    uchar* As1 = (uchar*)(pool + 16384);
    uchar* Bs1 = (uchar*)(pool + 24576);
    float* rowD = (float*)pool;            // [128][32], aliases pool post-release
    float* colD = (float*)(pool + 16384);  // [128][8]
    __shared__ int labLDS[256];

    const int tid = threadIdx.x;
    const int wave = tid >> 6, lane = tid & 63;

    int t = blockIdx.x, bi = 0;
    while (t >= 64 - bi) { t -= 64 - bi; ++bi; }
    const int bj = bi + t;
    const bool isDiag = (bi == bj);
    const int rowBase = bi * 128, colBase = bj * 128;

    // class-sorted rows: whole tile same class -> contributes 0 to D
    if (labelPerm[rowBase] == labelPerm[colBase + 127]) {
        if (tid < 128)       pD[(size_t)bj * N_ROWS + rowBase + tid] = 0.f;
        else if (!isDiag)    pD[(size_t)bi * N_ROWS + colBase + tid - 128] = 0.f;
        return;
    }

    labLDS[tid] = labelPerm[(tid < 128) ? (rowBase + tid) : (colBase + tid - 128)];
    TILE_SRC_SETUP(rowBase, colBase)
    __builtin_amdgcn_sched_barrier(0);

    f32x4 acc[4][4] = {};
    KLOOP_FP8()

    const int wr = wave >> 1, wc = wave & 1;
    const int lrow = lane & 15, lgrp = lane >> 4;
    float colAcc[4] = {0.f, 0.f, 0.f, 0.f};
    #pragma unroll
    for (int mi = 0; mi < 4; ++mi) {
        #pragma unroll
        for (int reg = 0; reg < 4; ++reg) {
            const int tr = wr * 64 + mi * 16 + lgrp * 4 + reg;
            const int rl = labLDS[tr];
            float rowAcc = 0.f;
            #pragma unroll
            for (int ni = 0; ni < 4; ++ni) {
                const int tc = wc * 64 + ni * 16 + lrow;
                float e = __builtin_amdgcn_exp2f(acc[mi][ni][reg] * EXPC);
                float ed = (rl != labLDS[128 + tc]) ? e : 0.f;
                rowAcc += ed;
                colAcc[ni] += ed;
            }
            rowD[tr * 32 + wc * 16 + lrow] = rowAcc;
        }
    }
    if (!isDiag) {
        #pragma unroll
        for (int ni = 0; ni < 4; ++ni) {
            const int tc = wc * 64 + ni * 16 + lrow;
            colD[tc * 8 + wr * 4 + lgrp] = colAcc[ni];
        }
    }
    __syncthreads();

    if (tid < 128) {
        const float* p = rowD + tid * 32;
        float s = 0.f;
        #pragma unroll
        for (int k = 0; k < 8; ++k) {
            f32x4 v = *reinterpret_cast<const f32x4*>(p + k * 4);
            s += v[0] + v[1] + v[2] + v[3];
        }
        pD[(size_t)bj * N_ROWS + rowBase + tid] = s;
    } else if (!isDiag) {
        const int c2 = tid - 128;
        const float* p = colD + c2 * 8;
        f32x4 v0 = *reinterpret_cast<const f32x4*>(p);
        f32x4 v1 = *reinterpret_cast<const f32x4*>(p + 4);
        pD[(size_t)bi * N_ROWS + colBase + c2] =
            v0[0] + v0[1] + v0[2] + v0[3] + v1[0] + v1[1] + v1[2] + v1[3];
    }
}

// ---------------- Kernel 3: same-class upper-tri tiles, 512-block stride ----
__global__ __launch_bounds__(256, 4) void phase3_loss(const uchar* __restrict__ xn8,
        const int* __restrict__ perm, const float* __restrict__ pD,
        const int* __restrict__ classStart, const int* __restrict__ cumTiles,
        float* __restrict__ partial)
{
    __shared__ __align__(16) char pool[32768];
    uchar* As0 = (uchar*)(pool);
    uchar* Bs0 = (uchar*)(pool + 8192);
    uchar* As1 = (uchar*)(pool + 16384);
    uchar* Bs1 = (uchar*)(pool + 24576);
    __shared__ float redF[256];
    __shared__ float DarrH[256];
    __shared__ float DarrR[128];
    __shared__ float DarrC[128];
    __shared__ int   meta[22];

    const int tid = threadIdx.x;
    const int wave = tid >> 6, lane = tid & 63;

    if (tid < 11) { meta[tid] = classStart[tid]; meta[11 + tid] = cumTiles[tid]; }
    __syncthreads();
    const int nTiles = meta[11 + 10];

    float tileSum = 0.f;
    for (int b = blockIdx.x; b < nTiles; b += 512) {
        __syncthreads();   // close previous iteration's LDS use

        int c = 0;
        while (c < 9 && b >= meta[11 + c + 1]) ++c;
        const int s = meta[c], e = meta[c + 1];
        const int nc = e - s;
        const int tps = (nc + 127) >> 7;
        int lt = b - meta[11 + c];
        int ti = 0;
        while (lt >= tps - ti) { lt -= tps - ti; ++ti; }
        const int tj = ti + lt;
        const bool isDiagT = (ti == tj);
        const int rowBase = s + ti * 128, colBase = s + tj * 128;

        // Darr gather (fixed order)
        {
            int r = rowBase + (tid & 127); if (r > N_ROWS - 1) r = N_ROWS - 1;
            const int half = tid >> 7;
            float d = 0.f;
            #pragma unroll 4
            for (int sl = half * 32; sl < half * 32 + 32; ++sl)
                d += pD[(size_t)sl * N_ROWS + r];
            DarrH[(tid & 127) * 2 + half] = d;
        }
        __syncthreads();
        if (tid < 128) DarrR[tid] = DarrH[tid * 2] + DarrH[tid * 2 + 1];
        __syncthreads();
        if (!isDiagT) {
            int r = colBase + (tid & 127); if (r > N_ROWS - 1) r = N_ROWS - 1;
            const int half = tid >> 7;
            float d = 0.f;
            #pragma unroll 4
            for (int sl = half * 32; sl < half * 32 + 32; ++sl)
                d += pD[(size_t)sl * N_ROWS + r];
            DarrH[(tid & 127) * 2 + half] = d;
            __syncthreads();
            if (tid < 128) DarrC[tid] = DarrH[tid * 2] + DarrH[tid * 2 + 1];
        }

        TILE_SRC_SETUP(rowBase, colBase)
        asm volatile("s_waitcnt vmcnt(0)" ::: "memory");   // clean vmcnt ledger
        __syncthreads();

        f32x4 acc[4][4] = {};
        KLOOP_FP8()

        const int wr = wave >> 1, wc = wave & 1;
        const int lrow = lane & 15, lgrp = lane >> 4;
        #pragma unroll
        for (int mi = 0; mi < 4; ++mi) {
            #pragma unroll
            for (int reg = 0; reg < 4; ++reg) {
                const int tr = wr * 64 + mi * 16 + lgrp * 4 + reg;
                const int r = rowBase + tr;
                if (r < e) {
                    const float Dr = DarrR[tr];
                    #pragma unroll
                    for (int ni = 0; ni < 4; ++ni) {
                        const int tc = wc * 64 + ni * 16 + lrow;
                        const int cg = colBase + tc;
                        if (cg < e) {
                            float sim = acc[mi][ni][reg];
                            float ev = __builtin_amdgcn_exp2f(sim * EXPC);
                            if (isDiagT) {
                                if (cg != r)
                                    tileSum += __logf(ev + Dr) - TEMP_INV * sim;
                            } else {
                                tileSum += __logf(ev + Dr) + __logf(ev + DarrC[tc])
                                         - 2.0f * TEMP_INV * sim;
                            }
                        }
                    }
                }
            }
        }
    }

    __syncthreads();
    redF[tid] = tileSum;
    __syncthreads();
    for (int st = 128; st > 0; st >>= 1) {
        if (tid < st) redF[tid] += redF[tid + st];
        __syncthreads();
    }
    if (tid == 0) partial[blockIdx.x] = redF[0];
}

// ---------------- Kernel 4: deterministic final reduction + scale ----------
__global__ void phase4_final(const float* __restrict__ partial, float* __restrict__ out)
{
    __shared__ float red[256];
    const int tid = threadIdx.x;
    float s = partial[tid] + partial[tid + 256];
    red[tid] = s;
    __syncthreads();
    for (int st = 128; st > 0; st >>= 1) {
        if (tid < st) red[tid] += red[tid + st];
        __syncthreads();
    }
    if (tid == 0) out[0] = red[0] * (1.0f / 16384.0f);
}

extern "C" void kernel_launch(void* const* d_in, const int* in_sizes, int n_in,
                              void* d_out, int out_size, void* d_ws, size_t ws_size,
                              hipStream_t stream)
{
    const float* logits = (const float*)d_in[0];
    const int*   label  = (const int*)d_in[1];
    float* out = (float*)d_out;

    char* ws = (char*)d_ws;
    uchar*  xn8       = (uchar*)(ws);                           // 2 MB
    float*  pD        = (float*)(ws + (2u << 20));              // 2 MB
    int*    perm      = (int*)(ws + (4u << 20));                // 32 KB
    int*    labelPerm = (int*)(ws + (4u << 20) + (32u << 10));  // 32 KB
    int*    classStart= (int*)(ws + (4u << 20) + (64u << 10));  // 64 B
    int*    cumTiles  = (int*)(ws + (4u << 20) + (64u << 10) + 256); // 64 B
    float*  partial   = (float*)(ws + (4u << 20) + (128u << 10));    // 2 KB

    hipLaunchKernelGGL(prep, dim3(2049), dim3(256), 0, stream,
                       logits, label, xn8, perm, labelPerm, classStart, cumTiles);
    hipLaunchKernelGGL(phase1_gemm, dim3(2080), dim3(256), 0, stream,
                       xn8, perm, labelPerm, pD);
    hipLaunchKernelGGL(phase3_loss, dim3(512), dim3(256), 0, stream,
                       xn8, perm, pD, classStart, cumTiles, partial);
    hipLaunchKernelGGL(phase4_final, dim3(1), dim3(256), 0, stream,
                       partial, out);
}

// Round 11
// 68.138 us; speedup vs baseline: 1.0726x; 1.0621x over previous
//
#include <hip/hip_runtime.h>
#include <cstdint>
#include <cstddef>

typedef float  f32x4  __attribute__((ext_vector_type(4)));
typedef long long i64;
typedef unsigned char uchar;

#define N_ROWS 8192
#define KDIM   256
#define TEMP_INV 2.0f
#define LOG2E  1.4426950408889634f
#define EXPC   (TEMP_INV * LOG2E)

#define AS1 __attribute__((address_space(1)))
#define AS3 __attribute__((address_space(3)))

// ---------------- Kernel 1: fused prep (R10-validated) ----------------
// Blocks 0..2047: normalize+fp8-cast rows UNPERMUTED. Block 2048: build perm.
__global__ __launch_bounds__(256) void prep(const float* __restrict__ logits,
        const int* __restrict__ label, uchar* __restrict__ xn8,
        int* __restrict__ perm, int* __restrict__ labelPerm,
        int* __restrict__ classStart, int* __restrict__ cumTiles)
{
    __shared__ int lcnt[256][10];
    __shared__ int cstart[11];
    __shared__ int ccount[10];
    const int tid = threadIdx.x;
    const int bid = blockIdx.x;

    if (bid < 2048) {   // normalize path (no perm dependency)
        const int p = bid * 4 + (tid >> 6);
        const int lane = tid & 63;
        float4 v = reinterpret_cast<const float4*>(logits + (size_t)p * KDIM)[lane];
        float ss = v.x*v.x + v.y*v.y + v.z*v.z + v.w*v.w;
        #pragma unroll
        for (int off = 32; off >= 1; off >>= 1) ss += __shfl_xor(ss, off, 64);
        float inv = 1.0f / fmaxf(sqrtf(ss), 1e-8f);
        int pk = __builtin_amdgcn_cvt_pk_fp8_f32(v.x * inv, v.y * inv, 0, false);
        pk     = __builtin_amdgcn_cvt_pk_fp8_f32(v.z * inv, v.w * inv, pk, true);
        reinterpret_cast<unsigned int*>(xn8 + (size_t)p * KDIM)[lane] = (unsigned int)pk;
        return;
    }

    // ---- permutation build (one block) ----
    const int wave = tid >> 6, lane = tid & 63;
    const int beg = tid * 32, end = beg + 32;
    int loc[10] = {0,0,0,0,0,0,0,0,0,0};
    for (int i = beg; i < end; ++i) {
        int c = label[i]; c = (c < 0) ? 0 : (c > 9 ? 9 : c);
        loc[c]++;
    }
    #pragma unroll
    for (int c = 0; c < 10; ++c) lcnt[tid][c] = loc[c];
    __syncthreads();

    for (int c = wave; c < 10; c += 4) {
        int s0 = lcnt[lane*4+0][c], s1 = lcnt[lane*4+1][c];
        int s2 = lcnt[lane*4+2][c], s3 = lcnt[lane*4+3][c];
        int tot = s0 + s1 + s2 + s3;
        int incl = tot;
        #pragma unroll
        for (int d = 1; d < 64; d <<= 1) {
            int up = __shfl_up(incl, d, 64);
            if (lane >= d) incl += up;
        }
        int excl = incl - tot;
        lcnt[lane*4+0][c] = excl;
        lcnt[lane*4+1][c] = excl + s0;
        lcnt[lane*4+2][c] = excl + s0 + s1;
        lcnt[lane*4+3][c] = excl + s0 + s1 + s2;
        if (lane == 63) ccount[c] = incl;
    }
    __syncthreads();

    if (tid == 0) {
        int run = 0, runT = 0;
        for (int c = 0; c < 10; ++c) {
            cstart[c] = run; classStart[c] = run;
            int tpc = (ccount[c] + 127) >> 7;
            cumTiles[c] = runT;
            run  += ccount[c];
            runT += tpc * (tpc + 1) / 2;     // upper-tri within class
        }
        cstart[10] = run; classStart[10] = run; cumTiles[10] = runT;
    }
    __syncthreads();

    int ofs[10];
    #pragma unroll
    for (int c = 0; c < 10; ++c) ofs[c] = lcnt[tid][c];
    for (int i = beg; i < end; ++i) {
        int c = label[i]; c = (c < 0) ? 0 : (c > 9 ? 9 : c);
        int pos = cstart[c] + ofs[c]++;
        perm[pos] = i;
        labelPerm[pos] = c;
    }
}

// ================= fp8 one-shot 128x128 tile core (K=256 fully staged) ======
// LDS per matrix: 128 rows x 256 B. Stored 16B-chunk slot for (row, logical
// chunk c) is  slot = c ^ (row&15)  -> bank-conflict-free-ish reads (2-4 way).
// Rule #21: linear LDS dest, pre-swizzled GLOBAL source, same XOR on ds_read.
__device__ __forceinline__ void stage_oneshot(const uchar* __restrict__ xn8,
        const int* __restrict__ perm, int rowBase, int colBase,
        uchar* As, uchar* Bs, int tid)
{
    const int t4 = tid >> 4;
    const int ch = (tid & 15) ^ t4;          // logical chunk, constant per thread
    #pragma unroll
    for (int i = 0; i < 8; ++i) {
        const int row = i * 16 + t4;         // row&15 == t4 for all i
        int rA = rowBase + row; if (rA > N_ROWS - 1) rA = N_ROWS - 1;
        int rB = colBase + row; if (rB > N_ROWS - 1) rB = N_ROWS - 1;
        const int lds_off = (i * 256 + tid) * 16;   // wave-uniform base + lane*16
        const uchar* gA = xn8 + (size_t)perm[rA] * KDIM + ch * 16;
        const uchar* gB = xn8 + (size_t)perm[rB] * KDIM + ch * 16;
        __builtin_amdgcn_global_load_lds((const AS1 void*)gA, (AS3 void*)(As + lds_off), 16, 0, 0);
        __builtin_amdgcn_global_load_lds((const AS1 void*)gB, (AS3 void*)(Bs + lds_off), 16, 0, 0);
    }
}

__device__ __forceinline__ void mfma_oneshot(const uchar* As, const uchar* Bs,
        f32x4 (&acc)[4][4], int wave, int lane)
{
    const int wr = wave >> 1, wc = wave & 1;
    const int lrow = lane & 15, kgrp = lane >> 4;
    const int ch2 = kgrp >> 1, half8 = (kgrp & 1) * 8;
    #pragma unroll
    for (int s = 0; s < 8; ++s) {
        const int c16 = s * 2 + ch2;         // logical 16B chunk for this K=32 step
        i64 a[4], b[4];
        #pragma unroll
        for (int mi = 0; mi < 4; ++mi) {
            const int row = wr*64 + mi*16 + lrow;
            a[mi] = *reinterpret_cast<const i64*>(As + (size_t)row * 256 + ((c16 ^ lrow) * 16) + half8);
        }
        #pragma unroll
        for (int ni = 0; ni < 4; ++ni) {
            const int row = wc*64 + ni*16 + lrow;
            b[ni] = *reinterpret_cast<const i64*>(Bs + (size_t)row * 256 + ((c16 ^ lrow) * 16) + half8);
        }
        #pragma unroll
        for (int mi = 0; mi < 4; ++mi)
            #pragma unroll
            for (int ni = 0; ni < 4; ++ni)
                acc[mi][ni] = __builtin_amdgcn_mfma_f32_16x16x32_fp8_fp8(a[mi], b[ni], acc[mi][ni], 0, 0, 0);
    }
}

// ---------------- Kernel 2: upper-tri 128-tiles (fp8) -> pD partials --------
__global__ __launch_bounds__(256, 2) void phase1_gemm(const uchar* __restrict__ xn8,
        const int* __restrict__ perm, const int* __restrict__ labelPerm,
        float* __restrict__ pD)
{
    __shared__ __align__(16) char pool[65536];
    uchar* As = (uchar*)(pool);
    uchar* Bs = (uchar*)(pool + 32768);
    float* rowD = (float*)pool;            // [128][32], aliases pool post-sync
    float* colD = (float*)(pool + 16384);  // [128][8]
    __shared__ int labLDS[256];

    const int tid = threadIdx.x;
    const int wave = tid >> 6, lane = tid & 63;

    int t = blockIdx.x, bi = 0;
    while (t >= 64 - bi) { t -= 64 - bi; ++bi; }
    const int bj = bi + t;
    const bool isDiag = (bi == bj);
    const int rowBase = bi * 128, colBase = bj * 128;

    // class-sorted rows: whole tile same class -> contributes 0 to D
    if (labelPerm[rowBase] == labelPerm[colBase + 127]) {
        if (tid < 128)       pD[(size_t)bj * N_ROWS + rowBase + tid] = 0.f;
        else if (!isDiag)    pD[(size_t)bi * N_ROWS + colBase + tid - 128] = 0.f;
        return;
    }

    stage_oneshot(xn8, perm, rowBase, colBase, As, Bs, tid);   // issue early
    labLDS[tid] = labelPerm[(tid < 128) ? (rowBase + tid) : (colBase + tid - 128)];
    __syncthreads();                                            // one drain

    f32x4 acc[4][4] = {};
    mfma_oneshot(As, Bs, acc, wave, lane);
    __syncthreads();                                            // release LDS

    const int wr = wave >> 1, wc = wave & 1;
    const int lrow = lane & 15, lgrp = lane >> 4;
    float colAcc[4] = {0.f, 0.f, 0.f, 0.f};
    #pragma unroll
    for (int mi = 0; mi < 4; ++mi) {
        #pragma unroll
        for (int reg = 0; reg < 4; ++reg) {
            const int tr = wr * 64 + mi * 16 + lgrp * 4 + reg;
            const int rl = labLDS[tr];
            float rowAcc = 0.f;
            #pragma unroll
            for (int ni = 0; ni < 4; ++ni) {
                const int tc = wc * 64 + ni * 16 + lrow;
                float e = __builtin_amdgcn_exp2f(acc[mi][ni][reg] * EXPC);
                float ed = (rl != labLDS[128 + tc]) ? e : 0.f;
                rowAcc += ed;
                colAcc[ni] += ed;
            }
            rowD[tr * 32 + wc * 16 + lrow] = rowAcc;
        }
    }
    if (!isDiag) {
        #pragma unroll
        for (int ni = 0; ni < 4; ++ni) {
            const int tc = wc * 64 + ni * 16 + lrow;
            colD[tc * 8 + wr * 4 + lgrp] = colAcc[ni];
        }
    }
    __syncthreads();

    if (tid < 128) {
        const float* p = rowD + tid * 32;
        float s = 0.f;
        #pragma unroll
        for (int k = 0; k < 8; ++k) {
            f32x4 v = *reinterpret_cast<const f32x4*>(p + k * 4);
            s += v[0] + v[1] + v[2] + v[3];
        }
        pD[(size_t)bj * N_ROWS + rowBase + tid] = s;
    } else if (!isDiag) {
        const int c2 = tid - 128;
        const float* p = colD + c2 * 8;
        f32x4 v0 = *reinterpret_cast<const f32x4*>(p);
        f32x4 v1 = *reinterpret_cast<const f32x4*>(p + 4);
        pD[(size_t)bi * N_ROWS + colBase + c2] =
            v0[0] + v0[1] + v0[2] + v0[3] + v1[0] + v1[1] + v1[2] + v1[3];
    }
}

// ---------------- Kernel 3: same-class upper-tri tiles (one-shot core) ------
__global__ __launch_bounds__(256, 2) void phase3_loss(const uchar* __restrict__ xn8,
        const int* __restrict__ perm, const float* __restrict__ pD,
        const int* __restrict__ classStart, const int* __restrict__ cumTiles,
        float* __restrict__ partial)
{
    __shared__ __align__(16) char pool[65536];
    uchar* As = (uchar*)(pool);
    uchar* Bs = (uchar*)(pool + 32768);
    __shared__ float redF[256];
    __shared__ float DarrH[256];
    __shared__ float DarrR[128];
    __shared__ float DarrC[128];
    __shared__ int   meta[22];

    const int tid = threadIdx.x;
    const int wave = tid >> 6, lane = tid & 63;

    if (tid < 11) { meta[tid] = classStart[tid]; meta[11 + tid] = cumTiles[tid]; }
    __syncthreads();
    const int nTiles = meta[11 + 10];

    float tileSum = 0.f;
    for (int b = blockIdx.x; b < nTiles; b += 512) {
        __syncthreads();   // close previous iteration's LDS use

        int c = 0;
        while (c < 9 && b >= meta[11 + c + 1]) ++c;
        const int s = meta[c], e = meta[c + 1];
        const int nc = e - s;
        const int tps = (nc + 127) >> 7;
        int lt = b - meta[11 + c];
        int ti = 0;
        while (lt >= tps - ti) { lt -= tps - ti; ++ti; }
        const int tj = ti + lt;
        const bool isDiagT = (ti == tj);
        const int rowBase = s + ti * 128, colBase = s + tj * 128;

        // issue the tile staging FIRST; its latency hides under the gathers
        stage_oneshot(xn8, perm, rowBase, colBase, As, Bs, tid);

        // Darr gather (fixed order)
        {
            int r = rowBase + (tid & 127); if (r > N_ROWS - 1) r = N_ROWS - 1;
            const int half = tid >> 7;
            float d = 0.f;
            #pragma unroll 4
            for (int sl = half * 32; sl < half * 32 + 32; ++sl)
                d += pD[(size_t)sl * N_ROWS + r];
            DarrH[(tid & 127) * 2 + half] = d;
        }
        __syncthreads();
        if (tid < 128) DarrR[tid] = DarrH[tid * 2] + DarrH[tid * 2 + 1];
        __syncthreads();
        if (!isDiagT) {
            int r = colBase + (tid & 127); if (r > N_ROWS - 1) r = N_ROWS - 1;
            const int half = tid >> 7;
            float d = 0.f;
            #pragma unroll 4
            for (int sl = half * 32; sl < half * 32 + 32; ++sl)
                d += pD[(size_t)sl * N_ROWS + r];
            DarrH[(tid & 127) * 2 + half] = d;
            __syncthreads();
            if (tid < 128) DarrC[tid] = DarrH[tid * 2] + DarrH[tid * 2 + 1];
        }
        __syncthreads();   // staging + gathers all complete

        f32x4 acc[4][4] = {};
        mfma_oneshot(As, Bs, acc, wave, lane);

        const int wr = wave >> 1, wc = wave & 1;
        const int lrow = lane & 15, lgrp = lane >> 4;
        #pragma unroll
        for (int mi = 0; mi < 4; ++mi) {
            #pragma unroll
            for (int reg = 0; reg < 4; ++reg) {
                const int tr = wr * 64 + mi * 16 + lgrp * 4 + reg;
                const int r = rowBase + tr;
                if (r < e) {
                    const float Dr = DarrR[tr];
                    #pragma unroll
                    for (int ni = 0; ni < 4; ++ni) {
                        const int tc = wc * 64 + ni * 16 + lrow;
                        const int cg = colBase + tc;
                        if (cg < e) {
                            float sim = acc[mi][ni][reg];
                            float ev = __builtin_amdgcn_exp2f(sim * EXPC);
                            if (isDiagT) {
                                if (cg != r)
                                    tileSum += __logf(ev + Dr) - TEMP_INV * sim;
                            } else {
                                tileSum += __logf(ev + Dr) + __logf(ev + DarrC[tc])
                                         - 2.0f * TEMP_INV * sim;
                            }
                        }
                    }
                }
            }
        }
    }

    __syncthreads();
    redF[tid] = tileSum;
    __syncthreads();
    for (int st = 128; st > 0; st >>= 1) {
        if (tid < st) redF[tid] += redF[tid + st];
        __syncthreads();
    }
    if (tid == 0) partial[blockIdx.x] = redF[0];
}

// ---------------- Kernel 4: deterministic final reduction + scale ----------
__global__ void phase4_final(const float* __restrict__ partial, float* __restrict__ out)
{
    __shared__ float red[256];
    const int tid = threadIdx.x;
    float s = partial[tid] + partial[tid + 256];
    red[tid] = s;
    __syncthreads();
    for (int st = 128; st > 0; st >>= 1) {
        if (tid < st) red[tid] += red[tid + st];
        __syncthreads();
    }
    if (tid == 0) out[0] = red[0] * (1.0f / 16384.0f);
}

extern "C" void kernel_launch(void* const* d_in, const int* in_sizes, int n_in,
                              void* d_out, int out_size, void* d_ws, size_t ws_size,
                              hipStream_t stream)
{
    const float* logits = (const float*)d_in[0];
    const int*   label  = (const int*)d_in[1];
    float* out = (float*)d_out;

    char* ws = (char*)d_ws;
    uchar*  xn8       = (uchar*)(ws);                           // 2 MB
    float*  pD        = (float*)(ws + (2u << 20));              // 2 MB
    int*    perm      = (int*)(ws + (4u << 20));                // 32 KB
    int*    labelPerm = (int*)(ws + (4u << 20) + (32u << 10));  // 32 KB
    int*    classStart= (int*)(ws + (4u << 20) + (64u << 10));  // 64 B
    int*    cumTiles  = (int*)(ws + (4u << 20) + (64u << 10) + 256); // 64 B
    float*  partial   = (float*)(ws + (4u << 20) + (128u << 10));    // 2 KB

    hipLaunchKernelGGL(prep, dim3(2049), dim3(256), 0, stream,
                       logits, label, xn8, perm, labelPerm, classStart, cumTiles);
    hipLaunchKernelGGL(phase1_gemm, dim3(2080), dim3(256), 0, stream,
                       xn8, perm, labelPerm, pD);
    hipLaunchKernelGGL(phase3_loss, dim3(512), dim3(256), 0, stream,
                       xn8, perm, pD, classStart, cumTiles, partial);
    hipLaunchKernelGGL(phase4_final, dim3(1), dim3(256), 0, stream,
                       partial, out);
}